// Round 3
// baseline (204.959 us; speedup 1.0000x reference)
//
#include <hip/hip_runtime.h>
#include <hip/hip_bf16.h>
#include <stdint.h>

// TrajectoryFK: L=65536 timesteps, J=22 joints, 6D-rotation inputs (fp32).
// Output: (L, 22, 3) fp32 joint positions.
// Decomposition: the only serial dependency is the affine scan
//   (R,p) <- (R @ d_t, p + R @ (d_t v_t))
// which is associative -> 3-phase chunked scan, then per-t joint tree.

#define LTOT 65536
#define ROW 132            // 22 joints * 6 floats per timestep (528 B, 16B-aligned)
#define CHUNK 64
#define NCHUNK (LTOT / CHUNK)   // 1024
#define P2PAD 13           // LDS stride pad (12 -> 13 breaks bank conflicts)

__device__ __forceinline__ void d6_to_mat(float a0, float a1, float a2,
                                          float a3, float a4, float a5,
                                          float R[9]) {
  // Gram-Schmidt; columns of R are b1,b2,b3 (row-major R[r*3+c]).
  float n1 = sqrtf(a0 * a0 + a1 * a1 + a2 * a2);
  float i1 = 1.0f / fmaxf(n1, 1e-12f);
  float b10 = a0 * i1, b11 = a1 * i1, b12 = a2 * i1;
  float d = b10 * a3 + b11 * a4 + b12 * a5;
  float c0 = a3 - d * b10, c1 = a4 - d * b11, c2 = a5 - d * b12;
  float n2 = sqrtf(c0 * c0 + c1 * c1 + c2 * c2);
  float i2 = 1.0f / fmaxf(n2, 1e-12f);
  float b20 = c0 * i2, b21 = c1 * i2, b22 = c2 * i2;
  float b30 = b11 * b22 - b12 * b21;
  float b31 = b12 * b20 - b10 * b22;
  float b32 = b10 * b21 - b11 * b20;
  R[0] = b10; R[1] = b20; R[2] = b30;
  R[3] = b11; R[4] = b21; R[5] = b31;
  R[6] = b12; R[7] = b22; R[8] = b32;
}

__device__ __forceinline__ void mat_mul(const float A[9], const float B[9], float C[9]) {
#pragma unroll
  for (int i = 0; i < 3; ++i) {
#pragma unroll
    for (int j = 0; j < 3; ++j)
      C[i * 3 + j] = A[i * 3 + 0] * B[0 + j] + A[i * 3 + 1] * B[3 + j] + A[i * 3 + 2] * B[6 + j];
  }
}

__device__ __forceinline__ void mat_vec(const float A[9], float x, float y, float z,
                                        float& ox, float& oy, float& oz) {
  ox = A[0] * x + A[1] * y + A[2] * z;
  oy = A[3] * x + A[4] * y + A[5] * z;
  oz = A[6] * x + A[7] * y + A[8] * z;
}

// ---------------- Phase 1: per-chunk sequential scan ----------------
// Each thread walks CHUNK timesteps, writes the inclusive LOCAL prefix
// (R[9], p[3]) for every t, plus the chunk aggregate.
__global__ __launch_bounds__(256) void fk_phase1(const float* __restrict__ pred,
                                                 float* __restrict__ loc,
                                                 float* __restrict__ agg) {
  int c = blockIdx.x * blockDim.x + threadIdx.x;
  if (c >= NCHUNK) return;
  float R[9] = {1.f, 0.f, 0.f, 0.f, 1.f, 0.f, 0.f, 0.f, 1.f};
  float p0 = 0.f, p1 = 0.f, p2 = 0.f;
  int t0 = c * CHUNK;
  for (int j = 0; j < CHUNK; ++j) {
    int t = t0 + j;
    const float4* q4 = (const float4*)(pred + (size_t)t * ROW);  // row start 16B-aligned
    float4 qa = q4[0];   // j0: v0 v1 v2 (w unused)
    float4 qb = q4[1];   // j0[4],j0[5] unused; j1: e0 e1
    float4 qc = q4[2];   // j1: e2 e3 e4 e5
    float d[9];
    d6_to_mat(qb.z, qb.w, qc.x, qc.y, qc.z, qc.w, d);  // joint1 delta rot
    float w0, w1, w2;
    mat_vec(d, qa.x, qa.y, qa.z, w0, w1, w2);  // w = d @ v
    float g0, g1, g2;
    mat_vec(R, w0, w1, w2, g0, g1, g2);        // p += R_prev @ w  (== R_new @ v)
    p0 += g0; p1 += g1; p2 += g2;
    float Rn[9];
    mat_mul(R, d, Rn);                         // R = R @ d
#pragma unroll
    for (int k = 0; k < 9; ++k) R[k] = Rn[k];
    float4* o = (float4*)(loc + (size_t)t * 12);   // 48B rows -> 16B aligned
    o[0] = make_float4(R[0], R[1], R[2], R[3]);
    o[1] = make_float4(R[4], R[5], R[6], R[7]);
    o[2] = make_float4(R[8], p0, p1, p2);
  }
  float4* a = (float4*)(agg + (size_t)c * 12);
  a[0] = make_float4(R[0], R[1], R[2], R[3]);
  a[1] = make_float4(R[4], R[5], R[6], R[7]);
  a[2] = make_float4(R[8], p0, p1, p2);
}

// ---------------- Phase 2: scan of chunk aggregates ----------------
// Single block, NCHUNK threads, Hillis-Steele inclusive scan in LDS,
// emits EXCLUSIVE prefixes. Composition: (A1,b1)∘(A2,b2) = (A1A2, b1 + A1 b2)
// where A1 precedes A2 in time.
__global__ __launch_bounds__(NCHUNK) void fk_phase2(const float* __restrict__ agg,
                                                    float* __restrict__ excl) {
  __shared__ float s[NCHUNK * P2PAD];
  int i = threadIdx.x;
#pragma unroll
  for (int k = 0; k < 12; ++k) s[i * P2PAD + k] = agg[i * 12 + k];
  __syncthreads();
  for (int off = 1; off < NCHUNK; off <<= 1) {
    float x[12];
    bool act = (i >= off);
    if (act) {
      const float* Lp = s + (size_t)(i - off) * P2PAD;  // earlier (left) element
      const float* Cp = s + (size_t)i * P2PAD;          // current element
      float AL[9], AC[9];
#pragma unroll
      for (int k = 0; k < 9; ++k) { AL[k] = Lp[k]; AC[k] = Cp[k]; }
      mat_mul(AL, AC, x);
      float bx, by, bz;
      mat_vec(AL, Cp[9], Cp[10], Cp[11], bx, by, bz);
      x[9] = Lp[9] + bx; x[10] = Lp[10] + by; x[11] = Lp[11] + bz;
    }
    __syncthreads();
    if (act) {
#pragma unroll
      for (int k = 0; k < 12; ++k) s[i * P2PAD + k] = x[k];
    }
    __syncthreads();
  }
  float* e = excl + (size_t)i * 12;
  if (i == 0) {
    e[0] = 1.f; e[1] = 0.f; e[2] = 0.f;
    e[3] = 0.f; e[4] = 1.f; e[5] = 0.f;
    e[6] = 0.f; e[7] = 0.f; e[8] = 1.f;
    e[9] = 0.f; e[10] = 0.f; e[11] = 0.f;
  } else {
    const float* sp = s + (size_t)(i - 1) * P2PAD;
#pragma unroll
    for (int k = 0; k < 12; ++k) e[k] = sp[k];
  }
}

// ---------------- Phase 3: per-timestep joint tree ----------------
__global__ __launch_bounds__(256) void fk_phase3(const float* __restrict__ pred,
                                                 const float* __restrict__ offs,
                                                 const float* __restrict__ loc,
                                                 const float* __restrict__ excl,
                                                 float* __restrict__ out) {
  int t = blockIdx.x * blockDim.x + threadIdx.x;
  const float* lp = loc + (size_t)t * 12;
  const float* ep = excl + (size_t)(t / CHUNK) * 12;
  float Rl[9], Re[9];
#pragma unroll
  for (int k = 0; k < 9; ++k) { Rl[k] = lp[k]; Re[k] = ep[k]; }
  float R[9];
  mat_mul(Re, Rl, R);                       // global R[t]
  float rx, ry, rz;
  mat_vec(Re, lp[9], lp[10], lp[11], rx, ry, rz);
  float ov[66];
  ov[0] = ep[9] + rx; ov[1] = ep[10] + ry; ov[2] = ep[11] + rz;  // root_pos

  const float* q = pred + (size_t)t * ROW;

#define CHILD(j, p, Rp)                                                        \
  {                                                                            \
    float ox, oy, oz;                                                          \
    mat_vec(Rp, offs[(j)*3 + 0], offs[(j)*3 + 1], offs[(j)*3 + 2], ox, oy, oz);\
    ov[(j)*3 + 0] = ov[(p)*3 + 0] + ox;                                        \
    ov[(j)*3 + 1] = ov[(p)*3 + 1] + oy;                                        \
    ov[(j)*3 + 2] = ov[(p)*3 + 2] + oz;                                        \
  }
#define ROTJ(j, Rp, Rj)                                                        \
  {                                                                            \
    float Mx[9];                                                               \
    d6_to_mat(q[(j)*6 + 0], q[(j)*6 + 1], q[(j)*6 + 2], q[(j)*6 + 3],          \
              q[(j)*6 + 4], q[(j)*6 + 5], Mx);                                 \
    mat_mul(Rp, Mx, Rj);                                                       \
  }

  // joint 1: rots[1] = R (no extra rotation)
  CHILD(1, 0, R);
  float r2[9], r3[9], r4[9];
  CHILD(2, 0, R); ROTJ(2, R, r2);
  CHILD(3, 0, R); ROTJ(3, R, r3);
  CHILD(4, 1, R); ROTJ(4, R, r4);
  float r5[9], r6[9], r7[9];
  CHILD(5, 2, r2); ROTJ(5, r2, r5);
  CHILD(6, 3, r3); ROTJ(6, r3, r6);
  CHILD(7, 4, r4); ROTJ(7, r4, r7);
  float r8[9], r9[9];
  CHILD(8, 5, r5); ROTJ(8, r5, r8);
  CHILD(9, 6, r6); ROTJ(9, r6, r9);
  CHILD(10, 7, r7);                 // leaf
  CHILD(11, 8, r8);                 // leaf
  float r12[9], r13[9], r14[9];
  CHILD(12, 9, r9); ROTJ(12, r9, r12);
  CHILD(13, 9, r9); ROTJ(13, r9, r13);
  CHILD(14, 9, r9); ROTJ(14, r9, r14);
  CHILD(15, 12, r12);               // leaf
  float r16[9], r17[9];
  CHILD(16, 13, r13); ROTJ(16, r13, r16);
  CHILD(17, 14, r14); ROTJ(17, r14, r17);
  float r18[9], r19[9];
  CHILD(18, 16, r16); ROTJ(18, r16, r18);
  CHILD(19, 17, r17); ROTJ(19, r17, r19);
  CHILD(20, 18, r18);               // leaf
  CHILD(21, 19, r19);               // leaf

  // Store 66 fp32 per t (264 B row, 8B-aligned) as 33 float2.
  float2* ob = (float2*)(out + (size_t)t * 66);
#pragma unroll
  for (int k = 0; k < 33; ++k) ob[k] = make_float2(ov[2 * k], ov[2 * k + 1]);
#undef CHILD
#undef ROTJ
}

extern "C" void kernel_launch(void* const* d_in, const int* in_sizes, int n_in,
                              void* d_out, int out_size, void* d_ws, size_t ws_size,
                              hipStream_t stream) {
  const float* pred = (const float*)d_in[0];   // (L, 22, 6) fp32
  const float* offs = (const float*)d_in[1];   // (22, 3)    fp32
  float* out = (float*)d_out;                  // (L, 22, 3) fp32

  float* ws = (float*)d_ws;
  float* loc  = ws;                                  // 12 * L floats (3 MB)
  float* agg  = ws + (size_t)12 * LTOT;              // 12 * NCHUNK
  float* excl = ws + (size_t)12 * LTOT + 12 * NCHUNK;

  fk_phase1<<<NCHUNK / 256, 256, 0, stream>>>(pred, loc, agg);
  fk_phase2<<<1, NCHUNK, 0, stream>>>(agg, excl);
  fk_phase3<<<LTOT / 256, 256, 0, stream>>>(pred, offs, loc, excl, out);
}

// Round 4
// 98.897 us; speedup vs baseline: 2.0724x; 2.0724x over previous
//
#include <hip/hip_runtime.h>
#include <hip/hip_bf16.h>
#include <stdint.h>

// TrajectoryFK: L=65536 timesteps, J=22 joints, 6D-rotation inputs (fp32).
// Output: (L, 22, 3) fp32 joint positions.
// The only serial dependency is the affine scan
//   (R,p) <- (R @ d_t, p + R @ (d_t v_t)),  element T_t = (d_t, d_t v_t),
//   compose(P, T) = (P.A @ T.A, P.b + P.A @ T.b)   [P earlier in time]
// R4 redesign: R3's phase1 (thread-serial 64-step chunks, 16 waves total) was
// latency-bound at 150 us (Occupancy 0.18%, VALUBusy 0.17%). Now: one lane
// per timestep, per-lane element transform (sqrt/div fully parallel), then
// 6-step __shfl_up wave scan + cross-wave LDS compose. 1024 waves.

#define LTOT 65536
#define ROW 132                 // 22 joints * 6 floats per timestep (528 B)
#define P1B 256                 // timesteps per phase-1 block
#define NBLK (LTOT / P1B)       // 256 block aggregates

struct Aff { float A[9]; float b[3]; };

__device__ __forceinline__ void d6_to_mat(float a0, float a1, float a2,
                                          float a3, float a4, float a5,
                                          float R[9]) {
  // Gram-Schmidt; columns of R are b1,b2,b3 (row-major R[r*3+c]).
  float n1 = sqrtf(a0 * a0 + a1 * a1 + a2 * a2);
  float i1 = 1.0f / fmaxf(n1, 1e-12f);
  float b10 = a0 * i1, b11 = a1 * i1, b12 = a2 * i1;
  float d = b10 * a3 + b11 * a4 + b12 * a5;
  float c0 = a3 - d * b10, c1 = a4 - d * b11, c2 = a5 - d * b12;
  float n2 = sqrtf(c0 * c0 + c1 * c1 + c2 * c2);
  float i2 = 1.0f / fmaxf(n2, 1e-12f);
  float b20 = c0 * i2, b21 = c1 * i2, b22 = c2 * i2;
  float b30 = b11 * b22 - b12 * b21;
  float b31 = b12 * b20 - b10 * b22;
  float b32 = b10 * b21 - b11 * b20;
  R[0] = b10; R[1] = b20; R[2] = b30;
  R[3] = b11; R[4] = b21; R[5] = b31;
  R[6] = b12; R[7] = b22; R[8] = b32;
}

__device__ __forceinline__ void mat_mul(const float A[9], const float B[9], float C[9]) {
#pragma unroll
  for (int i = 0; i < 3; ++i)
#pragma unroll
    for (int j = 0; j < 3; ++j)
      C[i * 3 + j] = A[i * 3 + 0] * B[0 + j] + A[i * 3 + 1] * B[3 + j] + A[i * 3 + 2] * B[6 + j];
}

__device__ __forceinline__ void mat_vec(const float A[9], float x, float y, float z,
                                        float& ox, float& oy, float& oz) {
  ox = A[0] * x + A[1] * y + A[2] * z;
  oy = A[3] * x + A[4] * y + A[5] * z;
  oz = A[6] * x + A[7] * y + A[8] * z;
}

__device__ __forceinline__ void compose(const Aff& P, const Aff& T, Aff& O) {
  mat_mul(P.A, T.A, O.A);
  float bx, by, bz;
  mat_vec(P.A, T.b[0], T.b[1], T.b[2], bx, by, bz);
  O.b[0] = P.b[0] + bx; O.b[1] = P.b[1] + by; O.b[2] = P.b[2] + bz;
}

__device__ __forceinline__ void aff_identity(Aff& v) {
  v.A[0] = 1.f; v.A[1] = 0.f; v.A[2] = 0.f;
  v.A[3] = 0.f; v.A[4] = 1.f; v.A[5] = 0.f;
  v.A[6] = 0.f; v.A[7] = 0.f; v.A[8] = 1.f;
  v.b[0] = 0.f; v.b[1] = 0.f; v.b[2] = 0.f;
}

// Inclusive Hillis-Steele scan across the 64-lane wave.
__device__ __forceinline__ void wave_scan(Aff& v, int lane) {
#pragma unroll
  for (int s = 1; s < 64; s <<= 1) {
    Aff u;
#pragma unroll
    for (int k = 0; k < 9; ++k) u.A[k] = __shfl_up(v.A[k], s, 64);
#pragma unroll
    for (int k = 0; k < 3; ++k) u.b[k] = __shfl_up(v.b[k], s, 64);
    if (lane >= s) { Aff t; compose(u, v, t); v = t; }
  }
}

// ---------------- Phase 1: block-local scan, one lane per timestep --------
__global__ __launch_bounds__(P1B) void fk_phase1(const float* __restrict__ pred,
                                                 float* __restrict__ loc,
                                                 float* __restrict__ agg) {
  int t = blockIdx.x * P1B + threadIdx.x;
  int lane = threadIdx.x & 63, wid = threadIdx.x >> 6;

  const float4* q4 = (const float4*)(pred + (size_t)t * ROW);  // 16B-aligned
  float4 qa = q4[0];   // j0: v0 v1 v2 .
  float4 qb = q4[1];   // . . e0 e1
  float4 qc = q4[2];   // e2 e3 e4 e5
  Aff v;
  d6_to_mat(qb.z, qb.w, qc.x, qc.y, qc.z, qc.w, v.A);          // d_t
  mat_vec(v.A, qa.x, qa.y, qa.z, v.b[0], v.b[1], v.b[2]);      // d_t @ v_t

  wave_scan(v, lane);                                          // intra-wave

  __shared__ float sagg[P1B / 64][12];
  if (lane == 63) {
#pragma unroll
    for (int k = 0; k < 9; ++k) sagg[wid][k] = v.A[k];
#pragma unroll
    for (int k = 0; k < 3; ++k) sagg[wid][9 + k] = v.b[k];
  }
  __syncthreads();

  Aff pre; aff_identity(pre);
  for (int w = 0; w < wid; ++w) {     // <=3 compositions, broadcast LDS reads
    Aff g, t2;
#pragma unroll
    for (int k = 0; k < 9; ++k) g.A[k] = sagg[w][k];
#pragma unroll
    for (int k = 0; k < 3; ++k) g.b[k] = sagg[w][9 + k];
    compose(pre, g, t2); pre = t2;
  }
  Aff f; compose(pre, v, f);          // block-local inclusive prefix

  float4* o = (float4*)(loc + (size_t)t * 12);
  o[0] = make_float4(f.A[0], f.A[1], f.A[2], f.A[3]);
  o[1] = make_float4(f.A[4], f.A[5], f.A[6], f.A[7]);
  o[2] = make_float4(f.A[8], f.b[0], f.b[1], f.b[2]);
  if (threadIdx.x == P1B - 1) {
    float4* a = (float4*)(agg + (size_t)blockIdx.x * 12);
    a[0] = make_float4(f.A[0], f.A[1], f.A[2], f.A[3]);
    a[1] = make_float4(f.A[4], f.A[5], f.A[6], f.A[7]);
    a[2] = make_float4(f.A[8], f.b[0], f.b[1], f.b[2]);
  }
}

// ---------------- Phase 2: scan of NBLK=256 block aggregates --------------
// Single block of 256 threads; same wave-scan primitive; writes EXCLUSIVE.
__global__ __launch_bounds__(NBLK) void fk_phase2(const float* __restrict__ agg,
                                                  float* __restrict__ excl) {
  int i = threadIdx.x, lane = i & 63, wid = i >> 6;
  Aff v;
  {
    const float4* a = (const float4*)(agg + (size_t)i * 12);
    float4 a0 = a[0], a1 = a[1], a2 = a[2];
    v.A[0] = a0.x; v.A[1] = a0.y; v.A[2] = a0.z; v.A[3] = a0.w;
    v.A[4] = a1.x; v.A[5] = a1.y; v.A[6] = a1.z; v.A[7] = a1.w;
    v.A[8] = a2.x; v.b[0] = a2.y; v.b[1] = a2.z; v.b[2] = a2.w;
  }
  wave_scan(v, lane);

  __shared__ float sagg[NBLK / 64][12];
  if (lane == 63) {
#pragma unroll
    for (int k = 0; k < 9; ++k) sagg[wid][k] = v.A[k];
#pragma unroll
    for (int k = 0; k < 3; ++k) sagg[wid][9 + k] = v.b[k];
  }
  __syncthreads();

  Aff pre; aff_identity(pre);
  for (int w = 0; w < wid; ++w) {
    Aff g, t2;
#pragma unroll
    for (int k = 0; k < 9; ++k) g.A[k] = sagg[w][k];
#pragma unroll
    for (int k = 0; k < 3; ++k) g.b[k] = sagg[w][9 + k];
    compose(pre, g, t2); pre = t2;
  }
  Aff f; compose(pre, v, f);          // inclusive[i]

  // exclusive[i] = inclusive[i-1]; lane 0 of wave w gets pre (= incl[64w-1]),
  // global element 0 gets identity (pre is identity for wid==0).
  Aff e;
#pragma unroll
  for (int k = 0; k < 9; ++k) e.A[k] = __shfl_up(f.A[k], 1, 64);
#pragma unroll
  for (int k = 0; k < 3; ++k) e.b[k] = __shfl_up(f.b[k], 1, 64);
  if (lane == 0) e = pre;

  float4* o = (float4*)(excl + (size_t)i * 12);
  o[0] = make_float4(e.A[0], e.A[1], e.A[2], e.A[3]);
  o[1] = make_float4(e.A[4], e.A[5], e.A[6], e.A[7]);
  o[2] = make_float4(e.A[8], e.b[0], e.b[1], e.b[2]);
}

// ---------------- Phase 3: per-timestep joint tree ----------------
__global__ __launch_bounds__(256) void fk_phase3(const float* __restrict__ pred,
                                                 const float* __restrict__ offs,
                                                 const float* __restrict__ loc,
                                                 const float* __restrict__ excl,
                                                 float* __restrict__ out) {
  int t = blockIdx.x * blockDim.x + threadIdx.x;
  const float* lp = loc + (size_t)t * 12;
  const float* ep = excl + (size_t)(t / P1B) * 12;
  float Rl[9], Re[9];
#pragma unroll
  for (int k = 0; k < 9; ++k) { Rl[k] = lp[k]; Re[k] = ep[k]; }
  float R[9];
  mat_mul(Re, Rl, R);                       // global R[t]
  float rx, ry, rz;
  mat_vec(Re, lp[9], lp[10], lp[11], rx, ry, rz);
  float ov[66];
  ov[0] = ep[9] + rx; ov[1] = ep[10] + ry; ov[2] = ep[11] + rz;  // root_pos

  const float* q = pred + (size_t)t * ROW;

#define CHILD(j, p, Rp)                                                        \
  {                                                                            \
    float ox, oy, oz;                                                          \
    mat_vec(Rp, offs[(j)*3 + 0], offs[(j)*3 + 1], offs[(j)*3 + 2], ox, oy, oz);\
    ov[(j)*3 + 0] = ov[(p)*3 + 0] + ox;                                        \
    ov[(j)*3 + 1] = ov[(p)*3 + 1] + oy;                                        \
    ov[(j)*3 + 2] = ov[(p)*3 + 2] + oz;                                        \
  }
#define ROTJ(j, Rp, Rj)                                                        \
  {                                                                            \
    float Mx[9];                                                               \
    d6_to_mat(q[(j)*6 + 0], q[(j)*6 + 1], q[(j)*6 + 2], q[(j)*6 + 3],          \
              q[(j)*6 + 4], q[(j)*6 + 5], Mx);                                 \
    mat_mul(Rp, Mx, Rj);                                                       \
  }

  CHILD(1, 0, R);
  float r2[9], r3[9], r4[9];
  CHILD(2, 0, R); ROTJ(2, R, r2);
  CHILD(3, 0, R); ROTJ(3, R, r3);
  CHILD(4, 1, R); ROTJ(4, R, r4);
  float r5[9], r6[9], r7[9];
  CHILD(5, 2, r2); ROTJ(5, r2, r5);
  CHILD(6, 3, r3); ROTJ(6, r3, r6);
  CHILD(7, 4, r4); ROTJ(7, r4, r7);
  float r8[9], r9[9];
  CHILD(8, 5, r5); ROTJ(8, r5, r8);
  CHILD(9, 6, r6); ROTJ(9, r6, r9);
  CHILD(10, 7, r7);                 // leaf
  CHILD(11, 8, r8);                 // leaf
  float r12[9], r13[9], r14[9];
  CHILD(12, 9, r9); ROTJ(12, r9, r12);
  CHILD(13, 9, r9); ROTJ(13, r9, r13);
  CHILD(14, 9, r9); ROTJ(14, r9, r14);
  CHILD(15, 12, r12);               // leaf
  float r16[9], r17[9];
  CHILD(16, 13, r13); ROTJ(16, r13, r16);
  CHILD(17, 14, r14); ROTJ(17, r14, r17);
  float r18[9], r19[9];
  CHILD(18, 16, r16); ROTJ(18, r16, r18);
  CHILD(19, 17, r17); ROTJ(19, r17, r19);
  CHILD(20, 18, r18);               // leaf
  CHILD(21, 19, r19);               // leaf

  float2* ob = (float2*)(out + (size_t)t * 66);
#pragma unroll
  for (int k = 0; k < 33; ++k) ob[k] = make_float2(ov[2 * k], ov[2 * k + 1]);
#undef CHILD
#undef ROTJ
}

extern "C" void kernel_launch(void* const* d_in, const int* in_sizes, int n_in,
                              void* d_out, int out_size, void* d_ws, size_t ws_size,
                              hipStream_t stream) {
  const float* pred = (const float*)d_in[0];   // (L, 22, 6) fp32
  const float* offs = (const float*)d_in[1];   // (22, 3)    fp32
  float* out = (float*)d_out;                  // (L, 22, 3) fp32

  float* ws = (float*)d_ws;
  float* loc  = ws;                                  // 12 * L floats (3 MB)
  float* agg  = ws + (size_t)12 * LTOT;              // 12 * NBLK
  float* excl = ws + (size_t)12 * LTOT + 12 * NBLK;

  fk_phase1<<<NBLK, P1B, 0, stream>>>(pred, loc, agg);
  fk_phase2<<<1, NBLK, 0, stream>>>(agg, excl);
  fk_phase3<<<LTOT / 256, 256, 0, stream>>>(pred, offs, loc, excl, out);
}